// Round 5
// baseline (1453.021 us; speedup 1.0000x reference)
//
#include <hip/hip_runtime.h>
#include <hip/hip_bf16.h>
#include <math.h>

#define NN 50000
#define EE 800000
#define HH 8
#define DD 16
#define HDIM 128
#define LL 6
#define GG 64
#define NDI 48
#define EDI 4
#define FFD 512
#define SCB ((NN + 1023) / 1024)   // scan blocks = 49

typedef __attribute__((ext_vector_type(8))) short short8;
typedef __attribute__((ext_vector_type(8))) unsigned short ushort8;
typedef __attribute__((ext_vector_type(4))) float floatx4;

__device__ __forceinline__ unsigned short f2bf(float f) {
  unsigned u = __builtin_bit_cast(unsigned, f);
  unsigned rnd = 0x7FFFu + ((u >> 16) & 1u);
  return (unsigned short)((u + rnd) >> 16);
}
__device__ __forceinline__ float bf2f(unsigned short u) {
  unsigned v = ((unsigned)u) << 16;
  return __builtin_bit_cast(float, v);
}

// ---------------- node input projection: x = h @ node_W + node_b (fp32) ----------------
__global__ void k_node_proj(const float* __restrict__ h, const float* __restrict__ W,
                            const float* __restrict__ b, float* __restrict__ x) {
  __shared__ float hs[32][NDI];
  int t = threadIdx.x;                 // 128
  int n0 = blockIdx.x * 32;
  for (int idx = t; idx < 32 * NDI; idx += 128) {
    int nb = idx / NDI, i = idx - nb * NDI;
    int node = n0 + nb;
    hs[nb][i] = (node < NN) ? h[node * NDI + i] : 0.f;
  }
  __syncthreads();
  float acc[32];
#pragma unroll
  for (int nb = 0; nb < 32; nb++) acc[nb] = 0.f;
  for (int i = 0; i < NDI; i++) {
    float w = W[i * HDIM + t];
#pragma unroll
    for (int nb = 0; nb < 32; nb++) acc[nb] += hs[nb][i] * w;
  }
  float bb = b[t];
  for (int nb = 0; nb < 32; nb++) {
    int node = n0 + nb;
    if (node < NN) x[node * HDIM + t] = acc[nb] + bb;
  }
}

// ------- weight fragment pre-pack: W[m][K][OC] fp32 -> [m][OC/16][K/32][64][8] bf16 -------
__global__ void k_pack(const float* __restrict__ W, unsigned short* __restrict__ dst,
                       int K, int OC, int nmat) {
  int KC = K >> 5, CT = OC >> 4;
  int total = nmat * CT * KC * 512;
  for (int i = blockIdx.x * 256 + threadIdx.x; i < total; i += gridDim.x * 256) {
    int j = i & 7;
    int lane = (i >> 3) & 63;
    int rest = i >> 9;
    int kc = rest % KC; rest /= KC;
    int ct = rest % CT; int m = rest / CT;
    int col = ct * 16 + (lane & 15);
    int k = kc * 32 + (lane >> 4) * 8 + j;
    dst[i] = f2bf(W[(size_t)m * K * OC + (size_t)k * OC + col]);
  }
}

// ------- combined edge-bias matrices: Wcomb[l] = edge_W @ Web[l]  [4x8], bcomb -------
__global__ void k_wcomb(const float* __restrict__ edge_W, const float* __restrict__ edge_b,
                        const float* __restrict__ Web, const float* __restrict__ beb,
                        float* __restrict__ Wcomb, float* __restrict__ bcomb) {
  int t = threadIdx.x;  // 256
  if (t < LL * EDI * HH) {  // 192
    int l = t / (EDI * HH);
    int i = (t / HH) % EDI;
    int hh = t % HH;
    float s = 0.f;
    for (int j = 0; j < HDIM; j++) s += edge_W[i * HDIM + j] * Web[(l * HDIM + j) * HH + hh];
    Wcomb[t] = s;
  } else if (t < LL * EDI * HH + LL * HH) {  // next 48
    int u = t - LL * EDI * HH;
    int l = u / HH, hh = u % HH;
    float s = beb[l * HH + hh];
    for (int j = 0; j < HDIM; j++) s += edge_b[j] * Web[(l * HDIM + j) * HH + hh];
    bcomb[u] = s;
  }
}

// ---------------- CSR build ----------------
__global__ void k_deg(const int* __restrict__ row, int* __restrict__ deg) {
  int e = blockIdx.x * 256 + threadIdx.x;
  if (e < EE) atomicAdd(&deg[row[e]], 1);
}

// stage 1: per-1024-chunk sums
__global__ void k_scan1(const int* __restrict__ deg, int* __restrict__ bsum) {
  __shared__ int red[256];
  int b = blockIdx.x, t = threadIdx.x;
  int base = b * 1024;
  int s = 0;
  for (int j = t; j < 1024; j += 256) {
    int i = base + j;
    s += (i < NN) ? deg[i] : 0;
  }
  red[t] = s;
  __syncthreads();
  for (int off = 128; off > 0; off >>= 1) {
    if (t < off) red[t] += red[t + off];
    __syncthreads();
  }
  if (t == 0) bsum[b] = red[0];
}

// stage 2: exclusive scan of the SCB chunk sums (+ grand total)
__global__ void k_scan2(int* __restrict__ bsum, int* __restrict__ starts) {
  if (threadIdx.x == 0) {
    int s = 0;
    for (int b = 0; b < SCB; b++) { int v = bsum[b]; bsum[b] = s; s += v; }
    starts[NN] = s;
  }
}

// stage 3: local scan within each chunk + chunk offset
__global__ void k_scan3(const int* __restrict__ deg, const int* __restrict__ bsum,
                        int* __restrict__ starts, int* __restrict__ cursor) {
  __shared__ int tsum[256];
  int b = blockIdx.x, t = threadIdx.x;
  int base = b * 1024 + t * 4;
  int v[4];
  int s = 0;
#pragma unroll
  for (int j = 0; j < 4; j++) {
    int i = base + j;
    v[j] = (i < NN) ? deg[i] : 0;
    s += v[j];
  }
  tsum[t] = s;
  __syncthreads();
  for (int off = 1; off < 256; off <<= 1) {
    int xv = (t >= off) ? tsum[t - off] : 0;
    __syncthreads();
    tsum[t] += xv;
    __syncthreads();
  }
  int excl = tsum[t] - s + bsum[b];
#pragma unroll
  for (int j = 0; j < 4; j++) {
    int i = base + j;
    if (i < NN) { starts[i] = excl; cursor[i] = excl; excl += v[j]; }
  }
}

__global__ void k_scatter(const int* __restrict__ row, int* __restrict__ cursor,
                          int* __restrict__ eids) {
  int e = blockIdx.x * 256 + threadIdx.x;
  if (e < EE) {
    int r = row[e];
    int pos = atomicAdd(&cursor[r], 1);
    eids[pos] = e;
  }
}

// ---------------- graph ranges from sorted batch: boundary detection ----------------
__global__ void k_gbounds(const int* __restrict__ batch, int* __restrict__ gstart) {
  int i = blockIdx.x * 256 + threadIdx.x;
  if (i >= NN) return;
  int b = batch[i];
  int prev = (i == 0) ? -1 : batch[i - 1];
  for (int g = prev + 1; g <= b; g++) gstart[g] = i;
  if (i == NN - 1) {
    for (int g = b + 1; g <= GG; g++) gstart[g] = NN;
  }
}

// ---------------- LN1 + QKV projection via MFMA: 64 nodes/block, 4 waves ----------------
__global__ __launch_bounds__(256) void k_ln_qkv_mfma(
    const float* __restrict__ x,
    const unsigned short* __restrict__ Wqf, const float* __restrict__ bq,
    const unsigned short* __restrict__ Wkf, const float* __restrict__ bk,
    const unsigned short* __restrict__ Wvf, const float* __restrict__ bv,
    const float* __restrict__ g, const float* __restrict__ be,
    unsigned short* __restrict__ q, unsigned short* __restrict__ k,
    unsigned short* __restrict__ v) {
  __shared__ unsigned short xn[64][136];
  int t = threadIdx.x;
  int n0 = blockIdx.x * 64;
  {
    int row = t >> 2, quad = t & 3;   // 4 lanes/row, 32 elems each
    int node = n0 + row;
    float xv[32];
    float s = 0.f, sq = 0.f;
    if (node < NN) {
      const float* xr = x + (size_t)node * HDIM + quad * 32;
#pragma unroll
      for (int c = 0; c < 8; c++) {
        float4 f = *(const float4*)(xr + c * 4);
        xv[c*4+0]=f.x; xv[c*4+1]=f.y; xv[c*4+2]=f.z; xv[c*4+3]=f.w;
      }
#pragma unroll
      for (int j = 0; j < 32; j++) { s += xv[j]; sq += xv[j]*xv[j]; }
    } else {
#pragma unroll
      for (int j = 0; j < 32; j++) xv[j] = 0.f;
    }
    s += __shfl_xor(s, 1); s += __shfl_xor(s, 2);
    sq += __shfl_xor(sq, 1); sq += __shfl_xor(sq, 2);
    float m = s * (1.f / HDIM);
    float rv = rsqrtf(sq * (1.f / HDIM) - m * m + 1e-5f);
#pragma unroll
    for (int cb = 0; cb < 4; cb++) {
      ushort8 u;
#pragma unroll
      for (int j = 0; j < 8; j++) {
        int col = quad * 32 + cb * 8 + j;
        u[j] = f2bf((xv[cb*8+j] - m) * rv * g[col] + be[col]);
      }
      *(ushort8*)&xn[row][quad * 32 + cb * 8] = u;
    }
  }
  __syncthreads();
  int w = t >> 6, lane = t & 63;
  int r0 = w * 16;
  short8 a[4];
#pragma unroll
  for (int kc = 0; kc < 4; kc++)
    a[kc] = *(const short8*)&xn[r0 + (lane & 15)][kc * 32 + (lane >> 4) * 8];
  const unsigned short* Wf[3] = {Wqf, Wkf, Wvf};
  const float* bias[3] = {bq, bk, bv};
  unsigned short* outp[3] = {q, k, v};
#pragma unroll
  for (int mm = 0; mm < 3; mm++) {
    const unsigned short* wf = Wf[mm];
    for (int ct = 0; ct < 8; ct++) {
      floatx4 acc = {0.f, 0.f, 0.f, 0.f};
#pragma unroll
      for (int kc = 0; kc < 4; kc++) {
        short8 b = *(const short8*)(wf + ((size_t)(ct * 4 + kc) * 64 + lane) * 8);
        acc = __builtin_amdgcn_mfma_f32_16x16x32_bf16(a[kc], b, acc, 0, 0, 0);
      }
      int col = ct * 16 + (lane & 15);
      float bb = bias[mm][col];
#pragma unroll
      for (int r = 0; r < 4; r++) {
        int rr = r0 + (lane >> 4) * 4 + r;
        int nd = n0 + rr;
        if (nd < NN) outp[mm][(size_t)nd * HDIM + col] = f2bf(acc[r] + bb);
      }
    }
  }
}

// ---------------- attention: one wave per node, 8 edges/chunk, 2-deep pipeline ----------
__global__ __launch_bounds__(256) void k_attn(
    const unsigned short* __restrict__ q, const unsigned short* __restrict__ k,
    const unsigned short* __restrict__ v, const float* __restrict__ efeat,
    const int* __restrict__ colArr, const int* __restrict__ eids,
    const int* __restrict__ starts,
    const float* __restrict__ Wcomb, const float* __restrict__ bcomb,
    unsigned short* __restrict__ out) {
  int t = threadIdx.x;
  int wave = t >> 6, lane = t & 63;
  int node = blockIdx.x * 4 + wave;
  if (node >= NN) return;
  int g = lane >> 4, d = lane & 15;
  int hh = d >> 1;                      // head owned by this lane

  float qf[8];
  {
    ushort8 q8 = *(const ushort8*)(q + (size_t)node * HDIM + d * 8);
#pragma unroll
    for (int j = 0; j < 8; j++) qf[j] = bf2f(q8[j]) * 0.25f;
  }
  float wc0 = Wcomb[0 * HH + hh], wc1 = Wcomb[1 * HH + hh];
  float wc2 = Wcomb[2 * HH + hh], wc3 = Wcomb[3 * HH + hh];
  float bc = bcomb[hh];

  int s0 = starts[node], s1 = starts[node + 1];
  float acc[8];
#pragma unroll
  for (int j = 0; j < 8; j++) acc[j] = 0.f;
  float lsum = 0.f;

  // slot A = chunk+g, slot B = chunk+4+g; chunk stride 8
  int iA = s0 + g, iB = s0 + 4 + g;
  int eA0 = (iA < s1) ? eids[iA] : -1;
  int cA0 = (eA0 >= 0) ? colArr[eA0] : 0;
  int eB0 = (iB < s1) ? eids[iB] : -1;
  int cB0 = (eB0 >= 0) ? colArr[eB0] : 0;
  int iA1 = s0 + 8 + g, iB1 = s0 + 12 + g;
  int eA1 = (iA1 < s1) ? eids[iA1] : -1;
  int cA1 = (eA1 >= 0) ? colArr[eA1] : 0;
  int eB1 = (iB1 < s1) ? eids[iB1] : -1;
  int cB1 = (eB1 >= 0) ? colArr[eB1] : 0;

  ushort8 kA = *(const ushort8*)(k + (size_t)cA0 * HDIM + d * 8);
  ushort8 vA = *(const ushort8*)(v + (size_t)cA0 * HDIM + d * 8);
  ushort8 kB = *(const ushort8*)(k + (size_t)cB0 * HDIM + d * 8);
  ushort8 vB = *(const ushort8*)(v + (size_t)cB0 * HDIM + d * 8);
  float4 efA = (eA0 >= 0) ? *(const float4*)(efeat + (size_t)eA0 * EDI)
                          : float4{0.f, 0.f, 0.f, 0.f};
  float4 efB = (eB0 >= 0) ? *(const float4*)(efeat + (size_t)eB0 * EDI)
                          : float4{0.f, 0.f, 0.f, 0.f};

  for (int base = s0; base < s1; base += 8) {
    // prefetch data for next chunk (addresses known)
    ushort8 kAn = *(const ushort8*)(k + (size_t)cA1 * HDIM + d * 8);
    ushort8 vAn = *(const ushort8*)(v + (size_t)cA1 * HDIM + d * 8);
    ushort8 kBn = *(const ushort8*)(k + (size_t)cB1 * HDIM + d * 8);
    ushort8 vBn = *(const ushort8*)(v + (size_t)cB1 * HDIM + d * 8);
    float4 efAn = (eA1 >= 0) ? *(const float4*)(efeat + (size_t)eA1 * EDI)
                             : float4{0.f, 0.f, 0.f, 0.f};
    float4 efBn = (eB1 >= 0) ? *(const float4*)(efeat + (size_t)eB1 * EDI)
                             : float4{0.f, 0.f, 0.f, 0.f};
    // ids for chunk+2
    int iA2 = base + 16 + g, iB2 = base + 20 + g;
    int eA2 = (iA2 < s1) ? eids[iA2] : -1;
    int cA2 = (eA2 >= 0) ? colArr[eA2] : 0;
    int eB2 = (iB2 < s1) ? eids[iB2] : -1;
    int cB2 = (eB2 >= 0) ? colArr[eB2] : 0;

    // compute slot A
    {
      float part = 0.f;
#pragma unroll
      for (int j = 0; j < 8; j++) part += qf[j] * bf2f(kA[j]);
      part += __shfl_xor(part, 1);
      float eb = bc + efA.x * wc0 + efA.y * wc1 + efA.z * wc2 + efA.w * wc3;
      float ex = (eA0 >= 0) ? __expf(part + eb) : 0.f;
      lsum += ex;
#pragma unroll
      for (int j = 0; j < 8; j++) acc[j] += ex * bf2f(vA[j]);
    }
    // compute slot B
    {
      float part = 0.f;
#pragma unroll
      for (int j = 0; j < 8; j++) part += qf[j] * bf2f(kB[j]);
      part += __shfl_xor(part, 1);
      float eb = bc + efB.x * wc0 + efB.y * wc1 + efB.z * wc2 + efB.w * wc3;
      float ex = (eB0 >= 0) ? __expf(part + eb) : 0.f;
      lsum += ex;
#pragma unroll
      for (int j = 0; j < 8; j++) acc[j] += ex * bf2f(vB[j]);
    }

    // rotate pipeline
    eA0 = eA1; cA0 = cA1; kA = kAn; vA = vAn; efA = efAn;
    eB0 = eB1; cB0 = cB1; kB = kBn; vB = vBn; efB = efBn;
    eA1 = eA2; cA1 = cA2; eB1 = eB2; cB1 = cB2;
  }

  // cross-group reduction (4 groups at lane stride 16)
#pragma unroll
  for (int j = 0; j < 8; j++) {
    acc[j] += __shfl_xor(acc[j], 16);
    acc[j] += __shfl_xor(acc[j], 32);
  }
  lsum += __shfl_xor(lsum, 16);
  lsum += __shfl_xor(lsum, 32);

  if (g == 0) {
    float inv = 1.f / (lsum + 1e-10f);
    ushort8 o;
#pragma unroll
    for (int j = 0; j < 8; j++) o[j] = f2bf(acc[j] * inv);
    *(ushort8*)(out + (size_t)node * HDIM + d * 8) = o;
  }
}

// ---------------- out-projection + residual via MFMA ----------------
__global__ __launch_bounds__(256) void k_oproj_mfma(
    const unsigned short* __restrict__ ao, const unsigned short* __restrict__ Wof,
    const float* __restrict__ bo, float* __restrict__ x) {
  __shared__ unsigned short aos[64][136];
  int t = threadIdx.x;
  int n0 = blockIdx.x * 64;
#pragma unroll
  for (int c = 0; c < 4; c++) {
    int elem = c * 2048 + t * 8;
    int row = elem >> 7, col = elem & 127;
    int nd = n0 + row;
    ushort8 u = {0, 0, 0, 0, 0, 0, 0, 0};
    if (nd < NN) u = *(const ushort8*)(ao + (size_t)nd * HDIM + col);
    *(ushort8*)&aos[row][col] = u;
  }
  __syncthreads();
  int w = t >> 6, lane = t & 63;
  int r0 = w * 16;
  short8 a[4];
#pragma unroll
  for (int kc = 0; kc < 4; kc++)
    a[kc] = *(const short8*)&aos[r0 + (lane & 15)][kc * 32 + (lane >> 4) * 8];
  for (int ct = 0; ct < 8; ct++) {
    floatx4 acc = {0.f, 0.f, 0.f, 0.f};
#pragma unroll
    for (int kc = 0; kc < 4; kc++) {
      short8 b = *(const short8*)(Wof + ((size_t)(ct * 4 + kc) * 64 + lane) * 8);
      acc = __builtin_amdgcn_mfma_f32_16x16x32_bf16(a[kc], b, acc, 0, 0, 0);
    }
    int col = ct * 16 + (lane & 15);
    float bb = bo[col];
#pragma unroll
    for (int r = 0; r < 4; r++) {
      int rr = r0 + (lane >> 4) * 4 + r;
      int nd = n0 + rr;
      if (nd < NN) {
        size_t idx = (size_t)nd * HDIM + col;
        x[idx] = x[idx] + acc[r] + bb;
      }
    }
  }
}

// ---------------- LN2 + FFN + residual via MFMA: 32 nodes/block ----------------
__global__ __launch_bounds__(256) void k_ffn_mfma(
    const float* __restrict__ xin,
    const unsigned short* __restrict__ W1f, const float* __restrict__ b1,
    const unsigned short* __restrict__ W2f, const float* __restrict__ b2,
    const float* __restrict__ g, const float* __restrict__ be,
    float* __restrict__ x) {
  __shared__ unsigned short xn[32][136];
  __shared__ unsigned short hs[32][520];
  int t = threadIdx.x;
  int n0 = blockIdx.x * 32;
  {
    int row = t >> 3, oct = t & 7;   // 8 lanes/row, 16 elems each
    int node = n0 + row;
    float xv[16];
    float s = 0.f, sq = 0.f;
    if (node < NN) {
      const float* xr = xin + (size_t)node * HDIM + oct * 16;
#pragma unroll
      for (int c = 0; c < 4; c++) {
        float4 f = *(const float4*)(xr + c * 4);
        xv[c*4+0]=f.x; xv[c*4+1]=f.y; xv[c*4+2]=f.z; xv[c*4+3]=f.w;
      }
#pragma unroll
      for (int j = 0; j < 16; j++) { s += xv[j]; sq += xv[j]*xv[j]; }
    } else {
#pragma unroll
      for (int j = 0; j < 16; j++) xv[j] = 0.f;
    }
    s += __shfl_xor(s, 1); s += __shfl_xor(s, 2); s += __shfl_xor(s, 4);
    sq += __shfl_xor(sq, 1); sq += __shfl_xor(sq, 2); sq += __shfl_xor(sq, 4);
    float m = s * (1.f / HDIM);
    float rv = rsqrtf(sq * (1.f / HDIM) - m * m + 1e-5f);
#pragma unroll
    for (int cb = 0; cb < 2; cb++) {
      ushort8 u;
#pragma unroll
      for (int j = 0; j < 8; j++) {
        int col = oct * 16 + cb * 8 + j;
        u[j] = f2bf((xv[cb*8+j] - m) * rv * g[col] + be[col]);
      }
      *(ushort8*)&xn[row][oct * 16 + cb * 8] = u;
    }
  }
  __syncthreads();
  int w = t >> 6, lane = t & 63;
  int rt = w & 1, r0 = rt * 16;
  int cthalf = w >> 1;
  short8 a[4];
#pragma unroll
  for (int kc = 0; kc < 4; kc++)
    a[kc] = *(const short8*)&xn[r0 + (lane & 15)][kc * 32 + (lane >> 4) * 8];
  // GEMM1: hidden = relu(xn @ W1 + b1), bf16 into LDS
  for (int ci = 0; ci < 16; ci++) {
    int ct = cthalf * 16 + ci;
    floatx4 acc = {0.f, 0.f, 0.f, 0.f};
#pragma unroll
    for (int kc = 0; kc < 4; kc++) {
      short8 b = *(const short8*)(W1f + ((size_t)(ct * 4 + kc) * 64 + lane) * 8);
      acc = __builtin_amdgcn_mfma_f32_16x16x32_bf16(a[kc], b, acc, 0, 0, 0);
    }
    int col = ct * 16 + (lane & 15);
    float bb = b1[col];
#pragma unroll
    for (int r = 0; r < 4; r++) {
      int rr = r0 + (lane >> 4) * 4 + r;
      hs[rr][col] = f2bf(fmaxf(acc[r] + bb, 0.f));
    }
  }
  __syncthreads();
  // GEMM2: out = hidden @ W2 + b2 + xin
  short8 ah[16];
#pragma unroll
  for (int kc = 0; kc < 16; kc++)
    ah[kc] = *(const short8*)&hs[r0 + (lane & 15)][kc * 32 + (lane >> 4) * 8];
  for (int ci = 0; ci < 4; ci++) {
    int ct = cthalf * 4 + ci;
    floatx4 acc = {0.f, 0.f, 0.f, 0.f};
#pragma unroll
    for (int kc = 0; kc < 16; kc++) {
      short8 b = *(const short8*)(W2f + ((size_t)(ct * 16 + kc) * 64 + lane) * 8);
      acc = __builtin_amdgcn_mfma_f32_16x16x32_bf16(ah[kc], b, acc, 0, 0, 0);
    }
    int col = ct * 16 + (lane & 15);
    float bb = b2[col];
#pragma unroll
    for (int r = 0; r < 4; r++) {
      int rr = r0 + (lane >> 4) * 4 + r;
      int nd = n0 + rr;
      if (nd < NN) {
        size_t idx = (size_t)nd * HDIM + col;
        x[idx] = xin[idx] + acc[r] + bb;
      }
    }
  }
}

// ---------------- final LN -> d_out (vectorized, 64 nodes/block) ----------------
__global__ __launch_bounds__(256) void k_final(
    const float* __restrict__ x, const float* __restrict__ g,
    const float* __restrict__ be, float* __restrict__ outx) {
  int t = threadIdx.x;
  int row = t >> 2, quad = t & 3;      // 4 lanes/row, 32 elems each
  int node = blockIdx.x * 64 + row;
  if (node >= NN) return;
  const float* xr = x + (size_t)node * HDIM + quad * 32;
  float xv[32];
  float s = 0.f, sq = 0.f;
#pragma unroll
  for (int c = 0; c < 8; c++) {
    float4 f = *(const float4*)(xr + c * 4);
    xv[c*4+0]=f.x; xv[c*4+1]=f.y; xv[c*4+2]=f.z; xv[c*4+3]=f.w;
  }
#pragma unroll
  for (int j = 0; j < 32; j++) { s += xv[j]; sq += xv[j]*xv[j]; }
  s += __shfl_xor(s, 1); s += __shfl_xor(s, 2);
  sq += __shfl_xor(sq, 1); sq += __shfl_xor(sq, 2);
  float m = s * (1.f / HDIM);
  float rv = rsqrtf(sq * (1.f / HDIM) - m * m + 1e-5f);
  float* orow = outx + (size_t)node * HDIM + quad * 32;
#pragma unroll
  for (int c = 0; c < 8; c++) {
    float4 o;
    int col = quad * 32 + c * 4;
    o.x = (xv[c*4+0] - m) * rv * g[col+0] + be[col+0];
    o.y = (xv[c*4+1] - m) * rv * g[col+1] + be[col+1];
    o.z = (xv[c*4+2] - m) * rv * g[col+2] + be[col+2];
    o.w = (xv[c*4+3] - m) * rv * g[col+3] + be[col+3];
    *(float4*)(orow + c * 4) = o;
  }
}

// ---------------- graph mean pooling (batch is sorted; counts from gstart) ----------------
__global__ void k_pool(const float* __restrict__ outx, const int* __restrict__ gstart,
                       float* __restrict__ outg) {
  __shared__ float part[4][HDIM];
  int g = blockIdx.x;
  int t = threadIdx.x;  // 512
  int hd = t & 127, p = t >> 7;
  int s0 = gstart[g];
  int c = gstart[g + 1] - s0;
  float s = 0.f;
  for (int i = p; i < c; i += 4) s += outx[(size_t)(s0 + i) * HDIM + hd];
  part[p][hd] = s;
  __syncthreads();
  if (p == 0) {
    float tot = part[0][hd] + part[1][hd] + part[2][hd] + part[3][hd];
    outg[g * HDIM + hd] = tot / fmaxf((float)c, 1.f);
  }
}

extern "C" void kernel_launch(void* const* d_in, const int* in_sizes, int n_in,
                              void* d_out, int out_size, void* d_ws, size_t ws_size,
                              hipStream_t stream) {
  const float* h      = (const float*)d_in[0];
  const float* e      = (const float*)d_in[1];
  const int*   eidx   = (const int*)d_in[2];
  const int*   batch  = (const int*)d_in[3];
  const float* node_W = (const float*)d_in[4];
  const float* node_b = (const float*)d_in[5];
  const float* edge_W = (const float*)d_in[6];
  const float* edge_b = (const float*)d_in[7];
  const float* Wq  = (const float*)d_in[8];
  const float* bq  = (const float*)d_in[9];
  const float* Wk  = (const float*)d_in[10];
  const float* bk  = (const float*)d_in[11];
  const float* Wv  = (const float*)d_in[12];
  const float* bv  = (const float*)d_in[13];
  const float* Wo  = (const float*)d_in[14];
  const float* bo  = (const float*)d_in[15];
  const float* Web = (const float*)d_in[16];
  const float* beb = (const float*)d_in[17];
  const float* W1  = (const float*)d_in[18];
  const float* b1  = (const float*)d_in[19];
  const float* W2  = (const float*)d_in[20];
  const float* b2  = (const float*)d_in[21];
  const float* g1  = (const float*)d_in[22];
  const float* be1 = (const float*)d_in[23];
  const float* g2  = (const float*)d_in[24];
  const float* be2 = (const float*)d_in[25];
  const float* gF  = (const float*)d_in[26];
  const float* bF  = (const float*)d_in[27];

  const int* rowArr = eidx;
  const int* colArr = eidx + EE;

  char* ws = (char*)d_ws;
  size_t off = 0;
  auto alloc = [&](size_t bytes) -> void* {
    void* p = ws + off;
    off = (off + bytes + 255) & ~(size_t)255;
    return p;
  };
  float* x    = (float*)alloc((size_t)NN * HDIM * 4);
  unsigned short* qb = (unsigned short*)alloc((size_t)NN * HDIM * 2);
  unsigned short* kb = (unsigned short*)alloc((size_t)NN * HDIM * 2);
  unsigned short* vb = (unsigned short*)alloc((size_t)NN * HDIM * 2);
  unsigned short* ao = (unsigned short*)alloc((size_t)NN * HDIM * 2);
  int* deg    = (int*)alloc((size_t)NN * 4);
  int* starts = (int*)alloc((size_t)(NN + 1) * 4);
  int* cursor = (int*)alloc((size_t)NN * 4);
  int* eids   = (int*)alloc((size_t)EE * 4);
  int* bsum   = (int*)alloc((size_t)SCB * 4);
  float* Wcomb = (float*)alloc((size_t)LL * EDI * HH * 4);
  float* bcomb = (float*)alloc((size_t)LL * HH * 4);
  int* gstart = (int*)alloc((size_t)(GG + 1) * 4);
  // fragment-packed bf16 weights
  const int QKV_FRAG = 8 * 4 * 512;    // 16384 elems per matrix per layer
  const int FFN_FRAG1 = 32 * 4 * 512;  // 65536
  const int FFN_FRAG2 = 8 * 16 * 512;  // 65536
  unsigned short* Wqf = (unsigned short*)alloc((size_t)LL * QKV_FRAG * 2);
  unsigned short* Wkf = (unsigned short*)alloc((size_t)LL * QKV_FRAG * 2);
  unsigned short* Wvf = (unsigned short*)alloc((size_t)LL * QKV_FRAG * 2);
  unsigned short* Wof = (unsigned short*)alloc((size_t)LL * QKV_FRAG * 2);
  unsigned short* W1f = (unsigned short*)alloc((size_t)LL * FFN_FRAG1 * 2);
  unsigned short* W2f = (unsigned short*)alloc((size_t)LL * FFN_FRAG2 * 2);

  hipMemsetAsync(deg, 0, (size_t)NN * 4, stream);

  k_node_proj<<<(NN + 31) / 32, 128, 0, stream>>>(h, node_W, node_b, x);
  k_wcomb<<<1, 256, 0, stream>>>(edge_W, edge_b, Web, beb, Wcomb, bcomb);
  k_pack<<<(LL * QKV_FRAG + 255) / 256, 256, 0, stream>>>(Wq, Wqf, HDIM, HDIM, LL);
  k_pack<<<(LL * QKV_FRAG + 255) / 256, 256, 0, stream>>>(Wk, Wkf, HDIM, HDIM, LL);
  k_pack<<<(LL * QKV_FRAG + 255) / 256, 256, 0, stream>>>(Wv, Wvf, HDIM, HDIM, LL);
  k_pack<<<(LL * QKV_FRAG + 255) / 256, 256, 0, stream>>>(Wo, Wof, HDIM, HDIM, LL);
  k_pack<<<(LL * FFN_FRAG1 + 255) / 256, 256, 0, stream>>>(W1, W1f, HDIM, FFD, LL);
  k_pack<<<(LL * FFN_FRAG2 + 255) / 256, 256, 0, stream>>>(W2, W2f, FFD, HDIM, LL);
  k_deg<<<(EE + 255) / 256, 256, 0, stream>>>(rowArr, deg);
  k_scan1<<<SCB, 256, 0, stream>>>(deg, bsum);
  k_scan2<<<1, 64, 0, stream>>>(bsum, starts);
  k_scan3<<<SCB, 256, 0, stream>>>(deg, bsum, starts, cursor);
  k_scatter<<<(EE + 255) / 256, 256, 0, stream>>>(rowArr, cursor, eids);
  k_gbounds<<<(NN + 255) / 256, 256, 0, stream>>>(batch, gstart);

  int nb64 = (NN + 63) / 64;
  int nb32 = (NN + 31) / 32;
  for (int l = 0; l < LL; l++) {
    k_ln_qkv_mfma<<<nb64, 256, 0, stream>>>(x,
        Wqf + (size_t)l * QKV_FRAG, bq + (size_t)l * HDIM,
        Wkf + (size_t)l * QKV_FRAG, bk + (size_t)l * HDIM,
        Wvf + (size_t)l * QKV_FRAG, bv + (size_t)l * HDIM,
        g1 + (size_t)l * HDIM, be1 + (size_t)l * HDIM, qb, kb, vb);
    k_attn<<<(NN + 3) / 4, 256, 0, stream>>>(qb, kb, vb, e, colArr, eids, starts,
        Wcomb + (size_t)l * EDI * HH, bcomb + (size_t)l * HH, ao);
    k_oproj_mfma<<<nb64, 256, 0, stream>>>(ao, Wof + (size_t)l * QKV_FRAG,
        bo + (size_t)l * HDIM, x);
    k_ffn_mfma<<<nb32, 256, 0, stream>>>(x,
        W1f + (size_t)l * FFN_FRAG1, b1 + (size_t)l * FFD,
        W2f + (size_t)l * FFN_FRAG2, b2 + (size_t)l * HDIM,
        g2 + (size_t)l * HDIM, be2 + (size_t)l * HDIM, x);
  }

  float* outx = (float*)d_out;
  float* outg = outx + (size_t)NN * HDIM;
  k_final<<<(NN + 63) / 64, 256, 0, stream>>>(x, gF, bF, outx);
  k_pool<<<GG, 512, 0, stream>>>(outx, gstart, outg);
}

// Round 6
// 1434.584 us; speedup vs baseline: 1.0129x; 1.0129x over previous
//
#include <hip/hip_runtime.h>
#include <hip/hip_bf16.h>
#include <math.h>

#define NN 50000
#define EE 800000
#define HH 8
#define DD 16
#define HDIM 128
#define LL 6
#define GG 64
#define NDI 48
#define EDI 4
#define FFD 512
#define SCB ((NN + 1023) / 1024)   // scan blocks = 49

typedef __attribute__((ext_vector_type(8))) short short8;
typedef __attribute__((ext_vector_type(8))) unsigned short ushort8;
typedef __attribute__((ext_vector_type(4))) float floatx4;

__device__ __forceinline__ unsigned short f2bf(float f) {
  unsigned u = __builtin_bit_cast(unsigned, f);
  unsigned rnd = 0x7FFFu + ((u >> 16) & 1u);
  return (unsigned short)((u + rnd) >> 16);
}
__device__ __forceinline__ float bf2f(unsigned short u) {
  unsigned v = ((unsigned)u) << 16;
  return __builtin_bit_cast(float, v);
}

// ---------------- node input projection: x = h @ node_W + node_b (fp32) ----------------
__global__ void k_node_proj(const float* __restrict__ h, const float* __restrict__ W,
                            const float* __restrict__ b, float* __restrict__ x) {
  __shared__ float hs[32][NDI];
  int t = threadIdx.x;                 // 128
  int n0 = blockIdx.x * 32;
  for (int idx = t; idx < 32 * NDI; idx += 128) {
    int nb = idx / NDI, i = idx - nb * NDI;
    int node = n0 + nb;
    hs[nb][i] = (node < NN) ? h[node * NDI + i] : 0.f;
  }
  __syncthreads();
  float acc[32];
#pragma unroll
  for (int nb = 0; nb < 32; nb++) acc[nb] = 0.f;
  for (int i = 0; i < NDI; i++) {
    float w = W[i * HDIM + t];
#pragma unroll
    for (int nb = 0; nb < 32; nb++) acc[nb] += hs[nb][i] * w;
  }
  float bb = b[t];
  for (int nb = 0; nb < 32; nb++) {
    int node = n0 + nb;
    if (node < NN) x[node * HDIM + t] = acc[nb] + bb;
  }
}

// ------- weight fragment pre-pack: W[m][K][OC] fp32 -> [m][OC/16][K/32][64][8] bf16 -------
__global__ void k_pack(const float* __restrict__ W, unsigned short* __restrict__ dst,
                       int K, int OC, int nmat) {
  int KC = K >> 5, CT = OC >> 4;
  int total = nmat * CT * KC * 512;
  for (int i = blockIdx.x * 256 + threadIdx.x; i < total; i += gridDim.x * 256) {
    int j = i & 7;
    int lane = (i >> 3) & 63;
    int rest = i >> 9;
    int kc = rest % KC; rest /= KC;
    int ct = rest % CT; int m = rest / CT;
    int col = ct * 16 + (lane & 15);
    int k = kc * 32 + (lane >> 4) * 8 + j;
    dst[i] = f2bf(W[(size_t)m * K * OC + (size_t)k * OC + col]);
  }
}

// ------- combined edge-bias matrices: Wcomb[l] = edge_W @ Web[l]  [4x8], bcomb -------
__global__ void k_wcomb(const float* __restrict__ edge_W, const float* __restrict__ edge_b,
                        const float* __restrict__ Web, const float* __restrict__ beb,
                        float* __restrict__ Wcomb, float* __restrict__ bcomb) {
  int t = threadIdx.x;  // 256
  if (t < LL * EDI * HH) {  // 192
    int l = t / (EDI * HH);
    int i = (t / HH) % EDI;
    int hh = t % HH;
    float s = 0.f;
    for (int j = 0; j < HDIM; j++) s += edge_W[i * HDIM + j] * Web[(l * HDIM + j) * HH + hh];
    Wcomb[t] = s;
  } else if (t < LL * EDI * HH + LL * HH) {  // next 48
    int u = t - LL * EDI * HH;
    int l = u / HH, hh = u % HH;
    float s = beb[l * HH + hh];
    for (int j = 0; j < HDIM; j++) s += edge_b[j] * Web[(l * HDIM + j) * HH + hh];
    bcomb[u] = s;
  }
}

// ---------------- CSR build ----------------
__global__ void k_deg(const int* __restrict__ row, int* __restrict__ deg) {
  int e = blockIdx.x * 256 + threadIdx.x;
  if (e < EE) atomicAdd(&deg[row[e]], 1);
}

// stage 1: per-1024-chunk sums
__global__ void k_scan1(const int* __restrict__ deg, int* __restrict__ bsum) {
  __shared__ int red[256];
  int b = blockIdx.x, t = threadIdx.x;
  int base = b * 1024;
  int s = 0;
  for (int j = t; j < 1024; j += 256) {
    int i = base + j;
    s += (i < NN) ? deg[i] : 0;
  }
  red[t] = s;
  __syncthreads();
  for (int off = 128; off > 0; off >>= 1) {
    if (t < off) red[t] += red[t + off];
    __syncthreads();
  }
  if (t == 0) bsum[b] = red[0];
}

// stage 2: exclusive scan of the SCB chunk sums (+ grand total)
__global__ void k_scan2(int* __restrict__ bsum, int* __restrict__ starts) {
  if (threadIdx.x == 0) {
    int s = 0;
    for (int b = 0; b < SCB; b++) { int v = bsum[b]; bsum[b] = s; s += v; }
    starts[NN] = s;
  }
}

// stage 3: local scan within each chunk + chunk offset
__global__ void k_scan3(const int* __restrict__ deg, const int* __restrict__ bsum,
                        int* __restrict__ starts, int* __restrict__ cursor) {
  __shared__ int tsum[256];
  int b = blockIdx.x, t = threadIdx.x;
  int base = b * 1024 + t * 4;
  int v[4];
  int s = 0;
#pragma unroll
  for (int j = 0; j < 4; j++) {
    int i = base + j;
    v[j] = (i < NN) ? deg[i] : 0;
    s += v[j];
  }
  tsum[t] = s;
  __syncthreads();
  for (int off = 1; off < 256; off <<= 1) {
    int xv = (t >= off) ? tsum[t - off] : 0;
    __syncthreads();
    tsum[t] += xv;
    __syncthreads();
  }
  int excl = tsum[t] - s + bsum[b];
#pragma unroll
  for (int j = 0; j < 4; j++) {
    int i = base + j;
    if (i < NN) { starts[i] = excl; cursor[i] = excl; excl += v[j]; }
  }
}

__global__ void k_scatter(const int* __restrict__ row, int* __restrict__ cursor,
                          int* __restrict__ eids) {
  int e = blockIdx.x * 256 + threadIdx.x;
  if (e < EE) {
    int r = row[e];
    int pos = atomicAdd(&cursor[r], 1);
    eids[pos] = e;
  }
}

// ---------------- graph ranges from sorted batch: boundary detection ----------------
__global__ void k_gbounds(const int* __restrict__ batch, int* __restrict__ gstart) {
  int i = blockIdx.x * 256 + threadIdx.x;
  if (i >= NN) return;
  int b = batch[i];
  int prev = (i == 0) ? -1 : batch[i - 1];
  for (int g = prev + 1; g <= b; g++) gstart[g] = i;
  if (i == NN - 1) {
    for (int g = b + 1; g <= GG; g++) gstart[g] = NN;
  }
}

// ---------------- LN1 + QKV projection via MFMA: 64 nodes/block, 4 waves ----------------
// q -> qb [node][128]; K/V -> interleaved kv [node][256] (K at 0..127, V at 128..255)
__global__ __launch_bounds__(256) void k_ln_qkv_mfma(
    const float* __restrict__ x,
    const unsigned short* __restrict__ Wqf, const float* __restrict__ bq,
    const unsigned short* __restrict__ Wkf, const float* __restrict__ bk,
    const unsigned short* __restrict__ Wvf, const float* __restrict__ bv,
    const float* __restrict__ g, const float* __restrict__ be,
    unsigned short* __restrict__ q, unsigned short* __restrict__ kv) {
  __shared__ unsigned short xn[64][136];
  int t = threadIdx.x;
  int n0 = blockIdx.x * 64;
  {
    int row = t >> 2, quad = t & 3;   // 4 lanes/row, 32 elems each
    int node = n0 + row;
    float xv[32];
    float s = 0.f, sq = 0.f;
    if (node < NN) {
      const float* xr = x + (size_t)node * HDIM + quad * 32;
#pragma unroll
      for (int c = 0; c < 8; c++) {
        float4 f = *(const float4*)(xr + c * 4);
        xv[c*4+0]=f.x; xv[c*4+1]=f.y; xv[c*4+2]=f.z; xv[c*4+3]=f.w;
      }
#pragma unroll
      for (int j = 0; j < 32; j++) { s += xv[j]; sq += xv[j]*xv[j]; }
    } else {
#pragma unroll
      for (int j = 0; j < 32; j++) xv[j] = 0.f;
    }
    s += __shfl_xor(s, 1); s += __shfl_xor(s, 2);
    sq += __shfl_xor(sq, 1); sq += __shfl_xor(sq, 2);
    float m = s * (1.f / HDIM);
    float rv = rsqrtf(sq * (1.f / HDIM) - m * m + 1e-5f);
#pragma unroll
    for (int cb = 0; cb < 4; cb++) {
      ushort8 u;
#pragma unroll
      for (int j = 0; j < 8; j++) {
        int col = quad * 32 + cb * 8 + j;
        u[j] = f2bf((xv[cb*8+j] - m) * rv * g[col] + be[col]);
      }
      *(ushort8*)&xn[row][quad * 32 + cb * 8] = u;
    }
  }
  __syncthreads();
  int w = t >> 6, lane = t & 63;
  int r0 = w * 16;
  short8 a[4];
#pragma unroll
  for (int kc = 0; kc < 4; kc++)
    a[kc] = *(const short8*)&xn[r0 + (lane & 15)][kc * 32 + (lane >> 4) * 8];
  const unsigned short* Wf[3] = {Wqf, Wkf, Wvf};
  const float* bias[3] = {bq, bk, bv};
#pragma unroll
  for (int mm = 0; mm < 3; mm++) {
    const unsigned short* wf = Wf[mm];
    for (int ct = 0; ct < 8; ct++) {
      floatx4 acc = {0.f, 0.f, 0.f, 0.f};
#pragma unroll
      for (int kc = 0; kc < 4; kc++) {
        short8 b = *(const short8*)(wf + ((size_t)(ct * 4 + kc) * 64 + lane) * 8);
        acc = __builtin_amdgcn_mfma_f32_16x16x32_bf16(a[kc], b, acc, 0, 0, 0);
      }
      int col = ct * 16 + (lane & 15);
      float bb = bias[mm][col];
#pragma unroll
      for (int r = 0; r < 4; r++) {
        int rr = r0 + (lane >> 4) * 4 + r;
        int nd = n0 + rr;
        if (nd < NN) {
          if (mm == 0) q[(size_t)nd * HDIM + col] = f2bf(acc[r] + bb);
          else if (mm == 1) kv[(size_t)nd * 256 + col] = f2bf(acc[r] + bb);
          else kv[(size_t)nd * 256 + 128 + col] = f2bf(acc[r] + bb);
        }
      }
    }
  }
}

// ---------------- attention: one 16-lane group per node, depth-4 edge pipeline --------
__global__ __launch_bounds__(256) void k_attn(
    const unsigned short* __restrict__ q, const unsigned short* __restrict__ kv,
    const float* __restrict__ efeat,
    const int* __restrict__ colArr, const int* __restrict__ eids,
    const int* __restrict__ starts,
    const float* __restrict__ Wcomb, const float* __restrict__ bcomb,
    unsigned short* __restrict__ out) {
  int t = threadIdx.x;
  int wave = t >> 6, lane = t & 63;
  int g = lane >> 4, d = lane & 15;
  int node = blockIdx.x * 16 + wave * 4 + g;
  if (node >= NN) return;
  int hh = d >> 1;                      // head owned by this lane

  float qf[8];
  {
    ushort8 q8 = *(const ushort8*)(q + (size_t)node * HDIM + d * 8);
#pragma unroll
    for (int j = 0; j < 8; j++) qf[j] = bf2f(q8[j]) * 0.25f;
  }
  float wc0 = Wcomb[0 * HH + hh], wc1 = Wcomb[1 * HH + hh];
  float wc2 = Wcomb[2 * HH + hh], wc3 = Wcomb[3 * HH + hh];
  float bc = bcomb[hh];

  int s0 = starts[node], s1 = starts[node + 1];
  float acc[8];
#pragma unroll
  for (int j = 0; j < 8; j++) acc[j] = 0.f;
  float lsum = 0.f;

  // depth-4 slots: data (k,v,eb) + pending ids (pc,pe) for the next edge of each slot
  ushort8 sk[4], sv[4];
  float seb[4];
  int pc[4], pe[4];

#pragma unroll
  for (int j = 0; j < 4; j++) {
    int i = s0 + j;
    int e = (i < s1) ? eids[i] : -1;
    int c = (e >= 0) ? colArr[e] : 0;
    const unsigned short* kr = kv + (size_t)c * 256 + d * 8;
    sk[j] = *(const ushort8*)kr;
    sv[j] = *(const ushort8*)(kr + 128);
    float4 ef = (e >= 0) ? *(const float4*)(efeat + (size_t)e * EDI)
                         : float4{0.f, 0.f, 0.f, 0.f};
    seb[j] = (e >= 0) ? (bc + ef.x * wc0 + ef.y * wc1 + ef.z * wc2 + ef.w * wc3)
                      : -1e30f;
  }
#pragma unroll
  for (int j = 0; j < 4; j++) {
    int i = s0 + 4 + j;
    int e = (i < s1) ? eids[i] : -1;
    pe[j] = e;
    pc[j] = (e >= 0) ? colArr[e] : 0;
  }

  for (int base = s0; base < s1; base += 4) {
#pragma unroll
    for (int j = 0; j < 4; j++) {
      // prefetch edge (base+4+j) into slot j
      int e = pe[j], c = pc[j];
      const unsigned short* kr = kv + (size_t)c * 256 + d * 8;
      ushort8 kn = *(const ushort8*)kr;
      ushort8 vn = *(const ushort8*)(kr + 128);
      float4 ef = (e >= 0) ? *(const float4*)(efeat + (size_t)e * EDI)
                           : float4{0.f, 0.f, 0.f, 0.f};
      // resolve ids for edge (base+8+j)
      int i2 = base + 8 + j;
      int e2 = (i2 < s1) ? eids[i2] : -1;
      int c2 = (e2 >= 0) ? colArr[e2] : 0;
      // compute current slot j (edge base+j); invalid slots have seb = -1e30 -> ex = 0
      float part = 0.f;
#pragma unroll
      for (int u = 0; u < 8; u++) part += qf[u] * bf2f(sk[j][u]);
      part += __shfl_xor(part, 1);
      float ex = __expf(part + seb[j]);
      lsum += ex;
#pragma unroll
      for (int u = 0; u < 8; u++) acc[u] += ex * bf2f(sv[j][u]);
      // rotate slot j
      sk[j] = kn; sv[j] = vn;
      seb[j] = (e >= 0) ? (bc + ef.x * wc0 + ef.y * wc1 + ef.z * wc2 + ef.w * wc3)
                        : -1e30f;
      pe[j] = e2; pc[j] = c2;
    }
  }

  // lane-local denominator: group sees all edges of its node; lane's head = d>>1
  float inv = 1.f / (lsum + 1e-10f);
  ushort8 o;
#pragma unroll
  for (int j = 0; j < 8; j++) o[j] = f2bf(acc[j] * inv);
  *(ushort8*)(out + (size_t)node * HDIM + d * 8) = o;
}

// ---------------- out-projection + residual via MFMA ----------------
__global__ __launch_bounds__(256) void k_oproj_mfma(
    const unsigned short* __restrict__ ao, const unsigned short* __restrict__ Wof,
    const float* __restrict__ bo, float* __restrict__ x) {
  __shared__ unsigned short aos[64][136];
  int t = threadIdx.x;
  int n0 = blockIdx.x * 64;
#pragma unroll
  for (int c = 0; c < 4; c++) {
    int elem = c * 2048 + t * 8;
    int row = elem >> 7, col = elem & 127;
    int nd = n0 + row;
    ushort8 u = {0, 0, 0, 0, 0, 0, 0, 0};
    if (nd < NN) u = *(const ushort8*)(ao + (size_t)nd * HDIM + col);
    *(ushort8*)&aos[row][col] = u;
  }
  __syncthreads();
  int w = t >> 6, lane = t & 63;
  int r0 = w * 16;
  short8 a[4];
#pragma unroll
  for (int kc = 0; kc < 4; kc++)
    a[kc] = *(const short8*)&aos[r0 + (lane & 15)][kc * 32 + (lane >> 4) * 8];
  for (int ct = 0; ct < 8; ct++) {
    floatx4 acc = {0.f, 0.f, 0.f, 0.f};
#pragma unroll
    for (int kc = 0; kc < 4; kc++) {
      short8 b = *(const short8*)(Wof + ((size_t)(ct * 4 + kc) * 64 + lane) * 8);
      acc = __builtin_amdgcn_mfma_f32_16x16x32_bf16(a[kc], b, acc, 0, 0, 0);
    }
    int col = ct * 16 + (lane & 15);
    float bb = bo[col];
#pragma unroll
    for (int r = 0; r < 4; r++) {
      int rr = r0 + (lane >> 4) * 4 + r;
      int nd = n0 + rr;
      if (nd < NN) {
        size_t idx = (size_t)nd * HDIM + col;
        x[idx] = x[idx] + acc[r] + bb;
      }
    }
  }
}

// ---------------- LN2 + FFN + residual via MFMA: 32 nodes/block ----------------
__global__ __launch_bounds__(256) void k_ffn_mfma(
    const float* __restrict__ xin,
    const unsigned short* __restrict__ W1f, const float* __restrict__ b1,
    const unsigned short* __restrict__ W2f, const float* __restrict__ b2,
    const float* __restrict__ g, const float* __restrict__ be,
    float* __restrict__ x) {
  __shared__ unsigned short xn[32][136];
  __shared__ unsigned short hs[32][520];
  int t = threadIdx.x;
  int n0 = blockIdx.x * 32;
  {
    int row = t >> 3, oct = t & 7;   // 8 lanes/row, 16 elems each
    int node = n0 + row;
    float xv[16];
    float s = 0.f, sq = 0.f;
    if (node < NN) {
      const float* xr = xin + (size_t)node * HDIM + oct * 16;
#pragma unroll
      for (int c = 0; c < 4; c++) {
        float4 f = *(const float4*)(xr + c * 4);
        xv[c*4+0]=f.x; xv[c*4+1]=f.y; xv[c*4+2]=f.z; xv[c*4+3]=f.w;
      }
#pragma unroll
      for (int j = 0; j < 16; j++) { s += xv[j]; sq += xv[j]*xv[j]; }
    } else {
#pragma unroll
      for (int j = 0; j < 16; j++) xv[j] = 0.f;
    }
    s += __shfl_xor(s, 1); s += __shfl_xor(s, 2); s += __shfl_xor(s, 4);
    sq += __shfl_xor(sq, 1); sq += __shfl_xor(sq, 2); sq += __shfl_xor(sq, 4);
    float m = s * (1.f / HDIM);
    float rv = rsqrtf(sq * (1.f / HDIM) - m * m + 1e-5f);
#pragma unroll
    for (int cb = 0; cb < 2; cb++) {
      ushort8 u;
#pragma unroll
      for (int j = 0; j < 8; j++) {
        int col = oct * 16 + cb * 8 + j;
        u[j] = f2bf((xv[cb*8+j] - m) * rv * g[col] + be[col]);
      }
      *(ushort8*)&xn[row][oct * 16 + cb * 8] = u;
    }
  }
  __syncthreads();
  int w = t >> 6, lane = t & 63;
  int rt = w & 1, r0 = rt * 16;
  int cthalf = w >> 1;
  short8 a[4];
#pragma unroll
  for (int kc = 0; kc < 4; kc++)
    a[kc] = *(const short8*)&xn[r0 + (lane & 15)][kc * 32 + (lane >> 4) * 8];
  // GEMM1: hidden = relu(xn @ W1 + b1), bf16 into LDS
  for (int ci = 0; ci < 16; ci++) {
    int ct = cthalf * 16 + ci;
    floatx4 acc = {0.f, 0.f, 0.f, 0.f};
#pragma unroll
    for (int kc = 0; kc < 4; kc++) {
      short8 b = *(const short8*)(W1f + ((size_t)(ct * 4 + kc) * 64 + lane) * 8);
      acc = __builtin_amdgcn_mfma_f32_16x16x32_bf16(a[kc], b, acc, 0, 0, 0);
    }
    int col = ct * 16 + (lane & 15);
    float bb = b1[col];
#pragma unroll
    for (int r = 0; r < 4; r++) {
      int rr = r0 + (lane >> 4) * 4 + r;
      hs[rr][col] = f2bf(fmaxf(acc[r] + bb, 0.f));
    }
  }
  __syncthreads();
  // GEMM2: out = hidden @ W2 + b2 + xin
  short8 ah[16];
#pragma unroll
  for (int kc = 0; kc < 16; kc++)
    ah[kc] = *(const short8*)&hs[r0 + (lane & 15)][kc * 32 + (lane >> 4) * 8];
  for (int ci = 0; ci < 4; ci++) {
    int ct = cthalf * 4 + ci;
    floatx4 acc = {0.f, 0.f, 0.f, 0.f};
#pragma unroll
    for (int kc = 0; kc < 16; kc++) {
      short8 b = *(const short8*)(W2f + ((size_t)(ct * 16 + kc) * 64 + lane) * 8);
      acc = __builtin_amdgcn_mfma_f32_16x16x32_bf16(ah[kc], b, acc, 0, 0, 0);
    }
    int col = ct * 16 + (lane & 15);
    float bb = b2[col];
#pragma unroll
    for (int r = 0; r < 4; r++) {
      int rr = r0 + (lane >> 4) * 4 + r;
      int nd = n0 + rr;
      if (nd < NN) {
        size_t idx = (size_t)nd * HDIM + col;
        x[idx] = xin[idx] + acc[r] + bb;
      }
    }
  }
}

// ---------------- final LN -> d_out (vectorized, 64 nodes/block) ----------------
__global__ __launch_bounds__(256) void k_final(
    const float* __restrict__ x, const float* __restrict__ g,
    const float* __restrict__ be, float* __restrict__ outx) {
  int t = threadIdx.x;
  int row = t >> 2, quad = t & 3;      // 4 lanes/row, 32 elems each
  int node = blockIdx.x * 64 + row;
  if (node >= NN) return;
  const float* xr = x + (size_t)node * HDIM + quad * 32;
  float xv[32];
  float s = 0.f, sq = 0.f;
#pragma unroll
  for (int c = 0; c < 8; c++) {
    float4 f = *(const float4*)(xr + c * 4);
    xv[c*4+0]=f.x; xv[c*4+1]=f.y; xv[c*4+2]=f.z; xv[c*4+3]=f.w;
  }
#pragma unroll
  for (int j = 0; j < 32; j++) { s += xv[j]; sq += xv[j]*xv[j]; }
  s += __shfl_xor(s, 1); s += __shfl_xor(s, 2);
  sq += __shfl_xor(sq, 1); sq += __shfl_xor(sq, 2);
  float m = s * (1.f / HDIM);
  float rv = rsqrtf(sq * (1.f / HDIM) - m * m + 1e-5f);
  float* orow = outx + (size_t)node * HDIM + quad * 32;
#pragma unroll
  for (int c = 0; c < 8; c++) {
    float4 o;
    int col = quad * 32 + c * 4;
    o.x = (xv[c*4+0] - m) * rv * g[col+0] + be[col+0];
    o.y = (xv[c*4+1] - m) * rv * g[col+1] + be[col+1];
    o.z = (xv[c*4+2] - m) * rv * g[col+2] + be[col+2];
    o.w = (xv[c*4+3] - m) * rv * g[col+3] + be[col+3];
    *(float4*)(orow + c * 4) = o;
  }
}

// ---------------- graph mean pooling (batch is sorted; counts from gstart) ----------------
__global__ void k_pool(const float* __restrict__ outx, const int* __restrict__ gstart,
                       float* __restrict__ outg) {
  __shared__ float part[4][HDIM];
  int g = blockIdx.x;
  int t = threadIdx.x;  // 512
  int hd = t & 127, p = t >> 7;
  int s0 = gstart[g];
  int c = gstart[g + 1] - s0;
  float s = 0.f;
  for (int i = p; i < c; i += 4) s += outx[(size_t)(s0 + i) * HDIM + hd];
  part[p][hd] = s;
  __syncthreads();
  if (p == 0) {
    float tot = part[0][hd] + part[1][hd] + part[2][hd] + part[3][hd];
    outg[g * HDIM + hd] = tot / fmaxf((float)c, 1.f);
  }
}

extern "C" void kernel_launch(void* const* d_in, const int* in_sizes, int n_in,
                              void* d_out, int out_size, void* d_ws, size_t ws_size,
                              hipStream_t stream) {
  const float* h      = (const float*)d_in[0];
  const float* e      = (const float*)d_in[1];
  const int*   eidx   = (const int*)d_in[2];
  const int*   batch  = (const int*)d_in[3];
  const float* node_W = (const float*)d_in[4];
  const float* node_b = (const float*)d_in[5];
  const float* edge_W = (const float*)d_in[6];
  const float* edge_b = (const float*)d_in[7];
  const float* Wq  = (const float*)d_in[8];
  const float* bq  = (const float*)d_in[9];
  const float* Wk  = (const float*)d_in[10];
  const float* bk  = (const float*)d_in[11];
  const float* Wv  = (const float*)d_in[12];
  const float* bv  = (const float*)d_in[13];
  const float* Wo  = (const float*)d_in[14];
  const float* bo  = (const float*)d_in[15];
  const float* Web = (const float*)d_in[16];
  const float* beb = (const float*)d_in[17];
  const float* W1  = (const float*)d_in[18];
  const float* b1  = (const float*)d_in[19];
  const float* W2  = (const float*)d_in[20];
  const float* b2  = (const float*)d_in[21];
  const float* g1  = (const float*)d_in[22];
  const float* be1 = (const float*)d_in[23];
  const float* g2  = (const float*)d_in[24];
  const float* be2 = (const float*)d_in[25];
  const float* gF  = (const float*)d_in[26];
  const float* bF  = (const float*)d_in[27];

  const int* rowArr = eidx;
  const int* colArr = eidx + EE;

  char* ws = (char*)d_ws;
  size_t off = 0;
  auto alloc = [&](size_t bytes) -> void* {
    void* p = ws + off;
    off = (off + bytes + 255) & ~(size_t)255;
    return p;
  };
  float* x    = (float*)alloc((size_t)NN * HDIM * 4);
  unsigned short* qb  = (unsigned short*)alloc((size_t)NN * HDIM * 2);
  unsigned short* kvb = (unsigned short*)alloc((size_t)NN * 256 * 2);
  unsigned short* ao  = (unsigned short*)alloc((size_t)NN * HDIM * 2);
  int* deg    = (int*)alloc((size_t)NN * 4);
  int* starts = (int*)alloc((size_t)(NN + 1) * 4);
  int* cursor = (int*)alloc((size_t)NN * 4);
  int* eids   = (int*)alloc((size_t)EE * 4);
  int* bsum   = (int*)alloc((size_t)SCB * 4);
  float* Wcomb = (float*)alloc((size_t)LL * EDI * HH * 4);
  float* bcomb = (float*)alloc((size_t)LL * HH * 4);
  int* gstart = (int*)alloc((size_t)(GG + 1) * 4);
  // fragment-packed bf16 weights
  const int QKV_FRAG = 8 * 4 * 512;    // 16384 elems per matrix per layer
  const int FFN_FRAG1 = 32 * 4 * 512;  // 65536
  const int FFN_FRAG2 = 8 * 16 * 512;  // 65536
  unsigned short* Wqf = (unsigned short*)alloc((size_t)LL * QKV_FRAG * 2);
  unsigned short* Wkf = (unsigned short*)alloc((size_t)LL * QKV_FRAG * 2);
  unsigned short* Wvf = (unsigned short*)alloc((size_t)LL * QKV_FRAG * 2);
  unsigned short* Wof = (unsigned short*)alloc((size_t)LL * QKV_FRAG * 2);
  unsigned short* W1f = (unsigned short*)alloc((size_t)LL * FFN_FRAG1 * 2);
  unsigned short* W2f = (unsigned short*)alloc((size_t)LL * FFN_FRAG2 * 2);

  hipMemsetAsync(deg, 0, (size_t)NN * 4, stream);

  k_node_proj<<<(NN + 31) / 32, 128, 0, stream>>>(h, node_W, node_b, x);
  k_wcomb<<<1, 256, 0, stream>>>(edge_W, edge_b, Web, beb, Wcomb, bcomb);
  k_pack<<<(LL * QKV_FRAG + 255) / 256, 256, 0, stream>>>(Wq, Wqf, HDIM, HDIM, LL);
  k_pack<<<(LL * QKV_FRAG + 255) / 256, 256, 0, stream>>>(Wk, Wkf, HDIM, HDIM, LL);
  k_pack<<<(LL * QKV_FRAG + 255) / 256, 256, 0, stream>>>(Wv, Wvf, HDIM, HDIM, LL);
  k_pack<<<(LL * QKV_FRAG + 255) / 256, 256, 0, stream>>>(Wo, Wof, HDIM, HDIM, LL);
  k_pack<<<(LL * FFN_FRAG1 + 255) / 256, 256, 0, stream>>>(W1, W1f, HDIM, FFD, LL);
  k_pack<<<(LL * FFN_FRAG2 + 255) / 256, 256, 0, stream>>>(W2, W2f, FFD, HDIM, LL);
  k_deg<<<(EE + 255) / 256, 256, 0, stream>>>(rowArr, deg);
  k_scan1<<<SCB, 256, 0, stream>>>(deg, bsum);
  k_scan2<<<1, 64, 0, stream>>>(bsum, starts);
  k_scan3<<<SCB, 256, 0, stream>>>(deg, bsum, starts, cursor);
  k_scatter<<<(EE + 255) / 256, 256, 0, stream>>>(rowArr, cursor, eids);
  k_gbounds<<<(NN + 255) / 256, 256, 0, stream>>>(batch, gstart);

  int nb64 = (NN + 63) / 64;
  int nb32 = (NN + 31) / 32;
  int nb16 = (NN + 15) / 16;
  for (int l = 0; l < LL; l++) {
    k_ln_qkv_mfma<<<nb64, 256, 0, stream>>>(x,
        Wqf + (size_t)l * QKV_FRAG, bq + (size_t)l * HDIM,
        Wkf + (size_t)l * QKV_FRAG, bk + (size_t)l * HDIM,
        Wvf + (size_t)l * QKV_FRAG, bv + (size_t)l * HDIM,
        g1 + (size_t)l * HDIM, be1 + (size_t)l * HDIM, qb, kvb);
    k_attn<<<nb16, 256, 0, stream>>>(qb, kvb, e, colArr, eids, starts,
        Wcomb + (size_t)l * EDI * HH, bcomb + (size_t)l * HH, ao);
    k_oproj_mfma<<<nb64, 256, 0, stream>>>(ao, Wof + (size_t)l * QKV_FRAG,
        bo + (size_t)l * HDIM, x);
    k_ffn_mfma<<<nb32, 256, 0, stream>>>(x,
        W1f + (size_t)l * FFN_FRAG1, b1 + (size_t)l * FFD,
        W2f + (size_t)l * FFN_FRAG2, b2 + (size_t)l * HDIM,
        g2 + (size_t)l * HDIM, be2 + (size_t)l * HDIM, x);
  }

  float* outx = (float*)d_out;
  float* outg = outx + (size_t)NN * HDIM;
  k_final<<<(NN + 63) / 64, 256, 0, stream>>>(x, gF, bF, outx);
  k_pool<<<GG, 512, 0, stream>>>(outx, gstart, outg);
}

// Round 7
// 1233.196 us; speedup vs baseline: 1.1783x; 1.1633x over previous
//
#include <hip/hip_runtime.h>
#include <hip/hip_bf16.h>
#include <math.h>

#define NN 50000
#define EE 800000
#define HH 8
#define DD 16
#define HDIM 128
#define LL 6
#define GG 64
#define NDI 48
#define EDI 4
#define FFD 512
#define SCB ((NN + 1023) / 1024)   // scan blocks = 49

typedef __attribute__((ext_vector_type(8))) short short8;
typedef __attribute__((ext_vector_type(8))) unsigned short ushort8;
typedef __attribute__((ext_vector_type(4))) float floatx4;
typedef __attribute__((ext_vector_type(2))) float f32x2;

__device__ __forceinline__ unsigned short f2bf(float f) {
  unsigned u = __builtin_bit_cast(unsigned, f);
  unsigned rnd = 0x7FFFu + ((u >> 16) & 1u);
  return (unsigned short)((u + rnd) >> 16);
}
__device__ __forceinline__ float bf2f(unsigned short u) {
  unsigned v = ((unsigned)u) << 16;
  return __builtin_bit_cast(float, v);
}

#ifdef __has_builtin
#if __has_builtin(__builtin_amdgcn_cvt_pk_f32_fp8) && __has_builtin(__builtin_amdgcn_cvt_pk_fp8_f32)
#define HW_FP8 1
#endif
#endif

// e4m3 encode (single value)
__device__ __forceinline__ unsigned char f2fp8(float f) {
#ifdef HW_FP8
  int p = __builtin_amdgcn_cvt_pk_fp8_f32(f, 0.f, 0, false);
  return (unsigned char)(p & 0xff);
#else
  unsigned u = __builtin_bit_cast(unsigned, f);
  unsigned s = (u >> 24) & 0x80u;
  unsigned au = u & 0x7fffffffu;
  float a = __builtin_bit_cast(float, au);
  if (a >= 448.f) return (unsigned char)(s | 0x7e);
  if (a < 0.0009765625f) return (unsigned char)s;  // < 2^-10 -> 0
  int e32 = (int)(au >> 23) - 127;
  if (e32 >= -6) {
    au += (1u << 19);  // round-to-nearest (half ulp of 3-bit mantissa)
    e32 = (int)(au >> 23) - 127;
    if (e32 > 8) return (unsigned char)(s | 0x7e);
    unsigned m = (au >> 20) & 7u;
    return (unsigned char)(s | (unsigned)((e32 + 7) << 3) | m);
  } else {
    int m = (int)(a * 512.f + 0.5f);
    if (m > 7) return (unsigned char)(s | 0x08);
    return (unsigned char)(s | (unsigned)m);
  }
#endif
}

// decode 8 fp8 (uint2) -> float[8]
__device__ __forceinline__ void fp8x8_dec(uint2 kw, float* f) {
#ifdef HW_FP8
  f32x2 a = __builtin_amdgcn_cvt_pk_f32_fp8((int)kw.x, false);
  f32x2 b = __builtin_amdgcn_cvt_pk_f32_fp8((int)kw.x, true);
  f32x2 c = __builtin_amdgcn_cvt_pk_f32_fp8((int)kw.y, false);
  f32x2 d = __builtin_amdgcn_cvt_pk_f32_fp8((int)kw.y, true);
  f[0] = a[0]; f[1] = a[1]; f[2] = b[0]; f[3] = b[1];
  f[4] = c[0]; f[5] = c[1]; f[6] = d[0]; f[7] = d[1];
#else
  unsigned w[2] = {kw.x, kw.y};
#pragma unroll
  for (int i = 0; i < 8; i++) {
    unsigned char bb = (unsigned char)((w[i >> 2] >> ((i & 3) * 8)) & 0xff);
    unsigned s = ((unsigned)bb & 0x80u) << 24;
    unsigned e = (bb >> 3) & 0xFu;
    unsigned m = bb & 7u;
    float v;
    if (e == 0) v = (float)m * 0.001953125f;
    else v = __builtin_bit_cast(float, ((e + 120u) << 23) | (m << 20));
    f[i] = __builtin_bit_cast(float, __builtin_bit_cast(unsigned, v) | s);
  }
#endif
}

// ---------------- node input projection: x = h @ node_W + node_b (fp32) ----------------
__global__ void k_node_proj(const float* __restrict__ h, const float* __restrict__ W,
                            const float* __restrict__ b, float* __restrict__ x) {
  __shared__ float hs[32][NDI];
  int t = threadIdx.x;                 // 128
  int n0 = blockIdx.x * 32;
  for (int idx = t; idx < 32 * NDI; idx += 128) {
    int nb = idx / NDI, i = idx - nb * NDI;
    int node = n0 + nb;
    hs[nb][i] = (node < NN) ? h[node * NDI + i] : 0.f;
  }
  __syncthreads();
  float acc[32];
#pragma unroll
  for (int nb = 0; nb < 32; nb++) acc[nb] = 0.f;
  for (int i = 0; i < NDI; i++) {
    float w = W[i * HDIM + t];
#pragma unroll
    for (int nb = 0; nb < 32; nb++) acc[nb] += hs[nb][i] * w;
  }
  float bb = b[t];
  for (int nb = 0; nb < 32; nb++) {
    int node = n0 + nb;
    if (node < NN) x[node * HDIM + t] = acc[nb] + bb;
  }
}

// ------- weight fragment pre-pack: W[m][K][OC] fp32 -> [m][OC/16][K/32][64][8] bf16 -------
__global__ void k_pack(const float* __restrict__ W, unsigned short* __restrict__ dst,
                       int K, int OC, int nmat) {
  int KC = K >> 5, CT = OC >> 4;
  int total = nmat * CT * KC * 512;
  for (int i = blockIdx.x * 256 + threadIdx.x; i < total; i += gridDim.x * 256) {
    int j = i & 7;
    int lane = (i >> 3) & 63;
    int rest = i >> 9;
    int kc = rest % KC; rest /= KC;
    int ct = rest % CT; int m = rest / CT;
    int col = ct * 16 + (lane & 15);
    int k = kc * 32 + (lane >> 4) * 8 + j;
    dst[i] = f2bf(W[(size_t)m * K * OC + (size_t)k * OC + col]);
  }
}

// ------- combined edge-bias matrices: Wcomb[l] = edge_W @ Web[l]  [4x8], bcomb -------
__global__ void k_wcomb(const float* __restrict__ edge_W, const float* __restrict__ edge_b,
                        const float* __restrict__ Web, const float* __restrict__ beb,
                        float* __restrict__ Wcomb, float* __restrict__ bcomb) {
  int t = threadIdx.x;  // 256
  if (t < LL * EDI * HH) {  // 192
    int l = t / (EDI * HH);
    int i = (t / HH) % EDI;
    int hh = t % HH;
    float s = 0.f;
    for (int j = 0; j < HDIM; j++) s += edge_W[i * HDIM + j] * Web[(l * HDIM + j) * HH + hh];
    Wcomb[t] = s;
  } else if (t < LL * EDI * HH + LL * HH) {  // next 48
    int u = t - LL * EDI * HH;
    int l = u / HH, hh = u % HH;
    float s = beb[l * HH + hh];
    for (int j = 0; j < HDIM; j++) s += edge_b[j] * Web[(l * HDIM + j) * HH + hh];
    bcomb[u] = s;
  }
}

// ---------------- CSR build ----------------
__global__ void k_deg(const int* __restrict__ row, int* __restrict__ deg) {
  int e = blockIdx.x * 256 + threadIdx.x;
  if (e < EE) atomicAdd(&deg[row[e]], 1);
}

__global__ void k_scan1(const int* __restrict__ deg, int* __restrict__ bsum) {
  __shared__ int red[256];
  int b = blockIdx.x, t = threadIdx.x;
  int base = b * 1024;
  int s = 0;
  for (int j = t; j < 1024; j += 256) {
    int i = base + j;
    s += (i < NN) ? deg[i] : 0;
  }
  red[t] = s;
  __syncthreads();
  for (int off = 128; off > 0; off >>= 1) {
    if (t < off) red[t] += red[t + off];
    __syncthreads();
  }
  if (t == 0) bsum[b] = red[0];
}

__global__ void k_scan2(int* __restrict__ bsum, int* __restrict__ starts) {
  if (threadIdx.x == 0) {
    int s = 0;
    for (int b = 0; b < SCB; b++) { int v = bsum[b]; bsum[b] = s; s += v; }
    starts[NN] = s;
  }
}

__global__ void k_scan3(const int* __restrict__ deg, const int* __restrict__ bsum,
                        int* __restrict__ starts, int* __restrict__ cursor) {
  __shared__ int tsum[256];
  int b = blockIdx.x, t = threadIdx.x;
  int base = b * 1024 + t * 4;
  int v[4];
  int s = 0;
#pragma unroll
  for (int j = 0; j < 4; j++) {
    int i = base + j;
    v[j] = (i < NN) ? deg[i] : 0;
    s += v[j];
  }
  tsum[t] = s;
  __syncthreads();
  for (int off = 1; off < 256; off <<= 1) {
    int xv = (t >= off) ? tsum[t - off] : 0;
    __syncthreads();
    tsum[t] += xv;
    __syncthreads();
  }
  int excl = tsum[t] - s + bsum[b];
#pragma unroll
  for (int j = 0; j < 4; j++) {
    int i = base + j;
    if (i < NN) { starts[i] = excl; cursor[i] = excl; excl += v[j]; }
  }
}

// scatter writes CSR edge ids AND direct column ids
__global__ void k_scatter(const int* __restrict__ row, const int* __restrict__ col,
                          int* __restrict__ cursor,
                          int* __restrict__ eids, int* __restrict__ cols) {
  int e = blockIdx.x * 256 + threadIdx.x;
  if (e < EE) {
    int r = row[e];
    int pos = atomicAdd(&cursor[r], 1);
    eids[pos] = e;
    cols[pos] = col[e];
  }
}

// ---------------- graph ranges from sorted batch: boundary detection ----------------
__global__ void k_gbounds(const int* __restrict__ batch, int* __restrict__ gstart) {
  int i = blockIdx.x * 256 + threadIdx.x;
  if (i >= NN) return;
  int b = batch[i];
  int prev = (i == 0) ? -1 : batch[i - 1];
  for (int g = prev + 1; g <= b; g++) gstart[g] = i;
  if (i == NN - 1) {
    for (int g = b + 1; g <= GG; g++) gstart[g] = NN;
  }
}

// ---------------- per-layer edge bias in CSR order: ebias[i][h] ----------------
__global__ void k_ebias(const int* __restrict__ eids, const float* __restrict__ efeat,
                        const float* __restrict__ Wcomb, const float* __restrict__ bcomb,
                        float* __restrict__ ebias) {
  int i = blockIdx.x * 256 + threadIdx.x;
  if (i >= EE) return;
  int e = eids[i];
  float4 ef = *(const float4*)(efeat + (size_t)e * EDI);
  float o[8];
#pragma unroll
  for (int hh = 0; hh < HH; hh++) {
    o[hh] = bcomb[hh] + ef.x * Wcomb[hh] + ef.y * Wcomb[8 + hh] +
            ef.z * Wcomb[16 + hh] + ef.w * Wcomb[24 + hh];
  }
  float4 o0 = {o[0], o[1], o[2], o[3]};
  float4 o1 = {o[4], o[5], o[6], o[7]};
  *(float4*)(ebias + (size_t)i * 8) = o0;
  *(float4*)(ebias + (size_t)i * 8 + 4) = o1;
}

// ---------------- LN1 + QKV projection via MFMA: 64 nodes/block, 4 waves ----------------
// outputs: q bf16 [node][128], kf8 fp8 [node][128], v bf16 [node][128]
__global__ __launch_bounds__(256) void k_ln_qkv_mfma(
    const float* __restrict__ x,
    const unsigned short* __restrict__ Wqf, const float* __restrict__ bq,
    const unsigned short* __restrict__ Wkf, const float* __restrict__ bk,
    const unsigned short* __restrict__ Wvf, const float* __restrict__ bv,
    const float* __restrict__ g, const float* __restrict__ be,
    unsigned short* __restrict__ q, unsigned char* __restrict__ kf8,
    unsigned short* __restrict__ v) {
  __shared__ unsigned short xn[64][136];
  int t = threadIdx.x;
  int n0 = blockIdx.x * 64;
  {
    int row = t >> 2, quad = t & 3;   // 4 lanes/row, 32 elems each
    int node = n0 + row;
    float xv[32];
    float s = 0.f, sq = 0.f;
    if (node < NN) {
      const float* xr = x + (size_t)node * HDIM + quad * 32;
#pragma unroll
      for (int c = 0; c < 8; c++) {
        float4 f = *(const float4*)(xr + c * 4);
        xv[c*4+0]=f.x; xv[c*4+1]=f.y; xv[c*4+2]=f.z; xv[c*4+3]=f.w;
      }
#pragma unroll
      for (int j = 0; j < 32; j++) { s += xv[j]; sq += xv[j]*xv[j]; }
    } else {
#pragma unroll
      for (int j = 0; j < 32; j++) xv[j] = 0.f;
    }
    s += __shfl_xor(s, 1); s += __shfl_xor(s, 2);
    sq += __shfl_xor(sq, 1); sq += __shfl_xor(sq, 2);
    float m = s * (1.f / HDIM);
    float rv = rsqrtf(sq * (1.f / HDIM) - m * m + 1e-5f);
#pragma unroll
    for (int cb = 0; cb < 4; cb++) {
      ushort8 u;
#pragma unroll
      for (int j = 0; j < 8; j++) {
        int col = quad * 32 + cb * 8 + j;
        u[j] = f2bf((xv[cb*8+j] - m) * rv * g[col] + be[col]);
      }
      *(ushort8*)&xn[row][quad * 32 + cb * 8] = u;
    }
  }
  __syncthreads();
  int w = t >> 6, lane = t & 63;
  int r0 = w * 16;
  short8 a[4];
#pragma unroll
  for (int kc = 0; kc < 4; kc++)
    a[kc] = *(const short8*)&xn[r0 + (lane & 15)][kc * 32 + (lane >> 4) * 8];
  const unsigned short* Wf[3] = {Wqf, Wkf, Wvf};
  const float* bias[3] = {bq, bk, bv};
#pragma unroll
  for (int mm = 0; mm < 3; mm++) {
    const unsigned short* wf = Wf[mm];
    for (int ct = 0; ct < 8; ct++) {
      floatx4 acc = {0.f, 0.f, 0.f, 0.f};
#pragma unroll
      for (int kc = 0; kc < 4; kc++) {
        short8 b = *(const short8*)(wf + ((size_t)(ct * 4 + kc) * 64 + lane) * 8);
        acc = __builtin_amdgcn_mfma_f32_16x16x32_bf16(a[kc], b, acc, 0, 0, 0);
      }
      int col = ct * 16 + (lane & 15);
      float bb = bias[mm][col];
#pragma unroll
      for (int r = 0; r < 4; r++) {
        int rr = r0 + (lane >> 4) * 4 + r;
        int nd = n0 + rr;
        if (nd < NN) {
          float val = acc[r] + bb;
          if (mm == 0) q[(size_t)nd * HDIM + col] = f2bf(val);
          else if (mm == 1) kf8[(size_t)nd * HDIM + col] = f2fp8(val);
          else v[(size_t)nd * HDIM + col] = f2bf(val);
        }
      }
    }
  }
}

// ---------------- attention: one 16-lane group per node, depth-4, fp8 K ----------------
__global__ __launch_bounds__(256) void k_attn(
    const unsigned short* __restrict__ q, const unsigned char* __restrict__ kf8,
    const unsigned short* __restrict__ v,
    const int* __restrict__ cols, const float* __restrict__ ebias,
    const int* __restrict__ starts,
    unsigned short* __restrict__ out) {
  int t = threadIdx.x;
  int wave = t >> 6, lane = t & 63;
  int g = lane >> 4, d = lane & 15;
  int node = blockIdx.x * 16 + wave * 4 + g;
  if (node >= NN) return;
  int hh = d >> 1;                      // head owned by this lane

  float qf[8];
  {
    ushort8 q8 = *(const ushort8*)(q + (size_t)node * HDIM + d * 8);
#pragma unroll
    for (int j = 0; j < 8; j++) qf[j] = bf2f(q8[j]) * 0.25f;
  }

  int s0 = starts[node], s1 = starts[node + 1];
  float acc[8];
#pragma unroll
  for (int j = 0; j < 8; j++) acc[j] = 0.f;
  float lsum = 0.f;

  // depth-4 slots: data (k fp8, v bf16, bias) + pending (col, bias) for next edge
  uint2 sk[4];
  ushort8 sv[4];
  float seb[4];
  int pc[4];
  float peb[4];

#pragma unroll
  for (int j = 0; j < 4; j++) {
    int i = s0 + j;
    bool ok = i < s1;
    int c = ok ? cols[i] : 0;
    sk[j] = *(const uint2*)(kf8 + (size_t)c * HDIM + d * 8);
    sv[j] = *(const ushort8*)(v + (size_t)c * HDIM + d * 8);
    seb[j] = ok ? ebias[(size_t)i * 8 + hh] : -1e30f;
  }
#pragma unroll
  for (int j = 0; j < 4; j++) {
    int i = s0 + 4 + j;
    bool ok = i < s1;
    pc[j] = ok ? cols[i] : 0;
    peb[j] = ok ? ebias[(size_t)i * 8 + hh] : -1e30f;
  }

  for (int base = s0; base < s1; base += 4) {
#pragma unroll
    for (int j = 0; j < 4; j++) {
      // stage data for edge (base+4+j)
      int c = pc[j];
      uint2 kn = *(const uint2*)(kf8 + (size_t)c * HDIM + d * 8);
      ushort8 vn = *(const ushort8*)(v + (size_t)c * HDIM + d * 8);
      float ebn = peb[j];
      // stage ids/bias for edge (base+8+j)
      int i2 = base + 8 + j;
      bool ok2 = i2 < s1;
      int c2 = ok2 ? cols[i2] : 0;
      float eb2 = ok2 ? ebias[(size_t)i2 * 8 + hh] : -1e30f;
      // compute current slot j (edge base+j); invalid -> seb=-1e30 -> ex=0
      float kf[8];
      fp8x8_dec(sk[j], kf);
      float part = 0.f;
#pragma unroll
      for (int u = 0; u < 8; u++) part += qf[u] * kf[u];
      part += __shfl_xor(part, 1);
      float ex = __expf(part + seb[j]);
      lsum += ex;
#pragma unroll
      for (int u = 0; u < 8; u++) acc[u] += ex * bf2f(sv[j][u]);
      // rotate
      sk[j] = kn; sv[j] = vn; seb[j] = ebn;
      pc[j] = c2; peb[j] = eb2;
    }
  }

  float inv = 1.f / (lsum + 1e-10f);
  ushort8 o;
#pragma unroll
  for (int j = 0; j < 8; j++) o[j] = f2bf(acc[j] * inv);
  *(ushort8*)(out + (size_t)node * HDIM + d * 8) = o;
}

// ------- fused: oproj + residual + LN2 + FFN + residual (32 nodes/block, 4 waves) -------
__global__ __launch_bounds__(256) void k_oproj_ffn(
    const unsigned short* __restrict__ ao, const unsigned short* __restrict__ Wof,
    const float* __restrict__ bo,
    const unsigned short* __restrict__ W1f, const float* __restrict__ b1,
    const unsigned short* __restrict__ W2f, const float* __restrict__ b2,
    const float* __restrict__ g, const float* __restrict__ be,
    float* __restrict__ x) {
  __shared__ unsigned short hs[32][520];   // GEMM1 hidden; first 8704 shorts reused as aos
  __shared__ float xr[32][132];            // fp32 residual stream tile
  __shared__ unsigned short xn[32][136];   // LN'd activations bf16
  unsigned short* aosp = &hs[0][0];        // aos[row][col] = aosp[row*136+col]
  int t = threadIdx.x;
  int n0 = blockIdx.x * 32;

  // Stage A: load ao tile (bf16) and x tile (fp32, coalesced)
#pragma unroll
  for (int c = 0; c < 2; c++) {
    int elem = c * 2048 + t * 8;
    int row = elem >> 7, col = elem & 127;
    int nd = n0 + row;
    ushort8 u = {0, 0, 0, 0, 0, 0, 0, 0};
    if (nd < NN) u = *(const ushort8*)(ao + (size_t)nd * HDIM + col);
    *(ushort8*)&aosp[row * 136 + col] = u;
  }
#pragma unroll
  for (int c = 0; c < 4; c++) {
    int elem = c * 1024 + t * 4;
    int row = elem >> 7, col = elem & 127;
    int nd = n0 + row;
    float4 f = {0.f, 0.f, 0.f, 0.f};
    if (nd < NN) f = *(const float4*)(x + (size_t)nd * HDIM + col);
    *(float4*)&xr[row][col] = f;
  }
  __syncthreads();

  int w = t >> 6, lane = t & 63;
  int rt = w & 1, r0 = rt * 16;
  int cthalf = w >> 1;

  // oproj: xr += ao @ Wo + bo
  {
    short8 a[4];
#pragma unroll
    for (int kc = 0; kc < 4; kc++)
      a[kc] = *(const short8*)&aosp[(r0 + (lane & 15)) * 136 + kc * 32 + (lane >> 4) * 8];
#pragma unroll
    for (int ci = 0; ci < 4; ci++) {
      int ct = cthalf * 4 + ci;
      floatx4 acc = {0.f, 0.f, 0.f, 0.f};
#pragma unroll
      for (int kc = 0; kc < 4; kc++) {
        short8 b = *(const short8*)(Wof + ((size_t)(ct * 4 + kc) * 64 + lane) * 8);
        acc = __builtin_amdgcn_mfma_f32_16x16x32_bf16(a[kc], b, acc, 0, 0, 0);
      }
      int col = ct * 16 + (lane & 15);
      float bb = bo[col];
#pragma unroll
      for (int r = 0; r < 4; r++) {
        int rr = r0 + (lane >> 4) * 4 + r;
        xr[rr][col] += acc[r] + bb;
      }
    }
  }
  __syncthreads();

  // LN2 from xr -> xn (bf16)
  {
    int row = t >> 3, oct = t & 7;   // 8 lanes/row, 16 elems each
    float xv[16];
    float s = 0.f, sq = 0.f;
#pragma unroll
    for (int jj = 0; jj < 16; jj++) {
      float f = xr[row][oct * 16 + jj];
      xv[jj] = f; s += f; sq += f * f;
    }
    s += __shfl_xor(s, 1); s += __shfl_xor(s, 2); s += __shfl_xor(s, 4);
    sq += __shfl_xor(sq, 1); sq += __shfl_xor(sq, 2); sq += __shfl_xor(sq, 4);
    float m = s * (1.f / HDIM);
    float rv = rsqrtf(sq * (1.f / HDIM) - m * m + 1e-5f);
#pragma unroll
    for (int cb = 0; cb < 2; cb++) {
      ushort8 u;
#pragma unroll
      for (int jj = 0; jj < 8; jj++) {
        int col = oct * 16 + cb * 8 + jj;
        u[jj] = f2bf((xv[cb*8+jj] - m) * rv * g[col] + be[col]);
      }
      *(ushort8*)&xn[row][oct * 16 + cb * 8] = u;
    }
  }
  __syncthreads();

  // GEMM1: hidden = relu(xn @ W1 + b1) -> hs (overwrites aos region; aos is dead)
  {
    short8 a[4];
#pragma unroll
    for (int kc = 0; kc < 4; kc++)
      a[kc] = *(const short8*)&xn[r0 + (lane & 15)][kc * 32 + (lane >> 4) * 8];
    for (int ci = 0; ci < 16; ci++) {
      int ct = cthalf * 16 + ci;
      floatx4 acc = {0.f, 0.f, 0.f, 0.f};
#pragma unroll
      for (int kc = 0; kc < 4; kc++) {
        short8 b = *(const short8*)(W1f + ((size_t)(ct * 4 + kc) * 64 + lane) * 8);
        acc = __builtin_amdgcn_mfma_f32_16x16x32_bf16(a[kc], b, acc, 0, 0, 0);
      }
      int col = ct * 16 + (lane & 15);
      float bb = b1[col];
#pragma unroll
      for (int r = 0; r < 4; r++) {
        int rr = r0 + (lane >> 4) * 4 + r;
        hs[rr][col] = f2bf(fmaxf(acc[r] + bb, 0.f));
      }
    }
  }
  __syncthreads();

  // GEMM2: x = hidden @ W2 + b2 + xr
  {
    short8 ah[16];
#pragma unroll
    for (int kc = 0; kc < 16; kc++)
      ah[kc] = *(const short8*)&hs[r0 + (lane & 15)][kc * 32 + (lane >> 4) * 8];
#pragma unroll
    for (int ci = 0; ci < 4; ci++) {
      int ct = cthalf * 4 + ci;
      floatx4 acc = {0.f, 0.f, 0.f, 0.f};
#pragma unroll
      for (int kc = 0; kc < 16; kc++) {
        short8 b = *(const short8*)(W2f + ((size_t)(ct * 16 + kc) * 64 + lane) * 8);
        acc = __builtin_amdgcn_mfma_f32_16x16x32_bf16(ah[kc], b, acc, 0, 0, 0);
      }
      int col = ct * 16 + (lane & 15);
      float bb = b2[col];
#pragma unroll
      for (int r = 0; r < 4; r++) {
        int rr = r0 + (lane >> 4) * 4 + r;
        int nd = n0 + rr;
        if (nd < NN) x[(size_t)nd * HDIM + col] = xr[rr][col] + acc[r] + bb;
      }
    }
  }
}

// ---------------- final LN -> d_out (vectorized, 64 nodes/block) ----------------
__global__ __launch_bounds__(256) void k_final(
    const float* __restrict__ x, const float* __restrict__ g,
    const float* __restrict__ be, float* __restrict__ outx) {
  int t = threadIdx.x;
  int row = t >> 2, quad = t & 3;      // 4 lanes/row, 32 elems each
  int node = blockIdx.x * 64 + row;
  if (node >= NN) return;
  const float* xr = x + (size_t)node * HDIM + quad * 32;
  float xv[32];
  float s = 0.f, sq = 0.f;
#pragma unroll
  for (int c = 0; c < 8; c++) {
    float4 f = *(const float4*)(xr + c * 4);
    xv[c*4+0]=f.x; xv[c*4+1]=f.y; xv[c*4+2]=f.z; xv[c*4+3]=f.w;
  }
#pragma unroll
  for (int j = 0; j < 32; j++) { s += xv[j]; sq += xv[j]*xv[j]; }
  s += __shfl_xor(s, 1); s += __shfl_xor(s, 2);
  sq += __shfl_xor(sq, 1); sq += __shfl_xor(sq, 2);
  float m = s * (1.f / HDIM);
  float rv = rsqrtf(sq * (1.f / HDIM) - m * m + 1e-5f);
  float* orow = outx + (size_t)node * HDIM + quad * 32;
#pragma unroll
  for (int c = 0; c < 8; c++) {
    float4 o;
    int col = quad * 32 + c * 4;
    o.x = (xv[c*4+0] - m) * rv * g[col+0] + be[col+0];
    o.y = (xv[c*4+1] - m) * rv * g[col+1] + be[col+1];
    o.z = (xv[c*4+2] - m) * rv * g[col+2] + be[col+2];
    o.w = (xv[c*4+3] - m) * rv * g[col+3] + be[col+3];
    *(float4*)(orow + c * 4) = o;
  }
}

// ---------------- graph mean pooling (batch is sorted; counts from gstart) ----------------
__global__ void k_pool(const float* __restrict__ outx, const int* __restrict__ gstart,
                       float* __restrict__ outg) {
  __shared__ float part[4][HDIM];
  int g = blockIdx.x;
  int t = threadIdx.x;  // 512
  int hd = t & 127, p = t >> 7;
  int s0 = gstart[g];
  int c = gstart[g + 1] - s0;
  float s = 0.f;
  for (int i = p; i < c; i += 4) s += outx[(size_t)(s0 + i) * HDIM + hd];
  part[p][hd] = s;
  __syncthreads();
  if (p == 0) {
    float tot = part[0][hd] + part[1][hd] + part[2][hd] + part[3][hd];
    outg[g * HDIM + hd] = tot / fmaxf((float)c, 1.f);
  }
}

extern "C" void kernel_launch(void* const* d_in, const int* in_sizes, int n_in,
                              void* d_out, int out_size, void* d_ws, size_t ws_size,
                              hipStream_t stream) {
  const float* h      = (const float*)d_in[0];
  const float* e      = (const float*)d_in[1];
  const int*   eidx   = (const int*)d_in[2];
  const int*   batch  = (const int*)d_in[3];
  const float* node_W = (const float*)d_in[4];
  const float* node_b = (const float*)d_in[5];
  const float* edge_W = (const float*)d_in[6];
  const float* edge_b = (const float*)d_in[7];
  const float* Wq  = (const float*)d_in[8];
  const float* bq  = (const float*)d_in[9];
  const float* Wk  = (const float*)d_in[10];
  const float* bk  = (const float*)d_in[11];
  const float* Wv  = (const float*)d_in[12];
  const float* bv  = (const float*)d_in[13];
  const float* Wo  = (const float*)d_in[14];
  const float* bo  = (const float*)d_in[15];
  const float* Web = (const float*)d_in[16];
  const float* beb = (const float*)d_in[17];
  const float* W1  = (const float*)d_in[18];
  const float* b1  = (const float*)d_in[19];
  const float* W2  = (const float*)d_in[20];
  const float* b2  = (const float*)d_in[21];
  const float* g1  = (const float*)d_in[22];
  const float* be1 = (const float*)d_in[23];
  const float* g2  = (const float*)d_in[24];
  const float* be2 = (const float*)d_in[25];
  const float* gF  = (const float*)d_in[26];
  const float* bF  = (const float*)d_in[27];

  const int* rowArr = eidx;
  const int* colArr = eidx + EE;

  char* ws = (char*)d_ws;
  size_t off = 0;
  auto alloc = [&](size_t bytes) -> void* {
    void* p = ws + off;
    off = (off + bytes + 255) & ~(size_t)255;
    return p;
  };
  float* x    = (float*)alloc((size_t)NN * HDIM * 4);
  unsigned short* qb  = (unsigned short*)alloc((size_t)NN * HDIM * 2);
  unsigned char*  kf8 = (unsigned char*)alloc((size_t)NN * HDIM);
  unsigned short* vb  = (unsigned short*)alloc((size_t)NN * HDIM * 2);
  unsigned short* ao  = (unsigned short*)alloc((size_t)NN * HDIM * 2);
  int* deg    = (int*)alloc((size_t)NN * 4);
  int* starts = (int*)alloc((size_t)(NN + 1) * 4);
  int* cursor = (int*)alloc((size_t)NN * 4);
  int* eids   = (int*)alloc((size_t)EE * 4);
  int* cols   = (int*)alloc((size_t)EE * 4);
  float* ebias = (float*)alloc((size_t)EE * HH * 4);
  int* bsum   = (int*)alloc((size_t)SCB * 4);
  float* Wcomb = (float*)alloc((size_t)LL * EDI * HH * 4);
  float* bcomb = (float*)alloc((size_t)LL * HH * 4);
  int* gstart = (int*)alloc((size_t)(GG + 1) * 4);
  // fragment-packed bf16 weights
  const int QKV_FRAG = 8 * 4 * 512;    // 16384 elems per matrix per layer
  const int FFN_FRAG1 = 32 * 4 * 512;  // 65536
  const int FFN_FRAG2 = 8 * 16 * 512;  // 65536
  unsigned short* Wqf = (unsigned short*)alloc((size_t)LL * QKV_FRAG * 2);
  unsigned short* Wkf = (unsigned short*)alloc((size_t)LL * QKV_FRAG * 2);
  unsigned short* Wvf = (unsigned short*)alloc((size_t)LL * QKV_FRAG * 2);
  unsigned short* Wof = (unsigned short*)alloc((size_t)LL * QKV_FRAG * 2);
  unsigned short* W1f = (unsigned short*)alloc((size_t)LL * FFN_FRAG1 * 2);
  unsigned short* W2f = (unsigned short*)alloc((size_t)LL * FFN_FRAG2 * 2);

  hipMemsetAsync(deg, 0, (size_t)NN * 4, stream);

  k_node_proj<<<(NN + 31) / 32, 128, 0, stream>>>(h, node_W, node_b, x);
  k_wcomb<<<1, 256, 0, stream>>>(edge_W, edge_b, Web, beb, Wcomb, bcomb);
  k_pack<<<(LL * QKV_FRAG + 255) / 256, 256, 0, stream>>>(Wq, Wqf, HDIM, HDIM, LL);
  k_pack<<<(LL * QKV_FRAG + 255) / 256, 256, 0, stream>>>(Wk, Wkf, HDIM, HDIM, LL);
  k_pack<<<(LL * QKV_FRAG + 255) / 256, 256, 0, stream>>>(Wv, Wvf, HDIM, HDIM, LL);
  k_pack<<<(LL * QKV_FRAG + 255) / 256, 256, 0, stream>>>(Wo, Wof, HDIM, HDIM, LL);
  k_pack<<<(LL * FFN_FRAG1 + 255) / 256, 256, 0, stream>>>(W1, W1f, HDIM, FFD, LL);
  k_pack<<<(LL * FFN_FRAG2 + 255) / 256, 256, 0, stream>>>(W2, W2f, FFD, HDIM, LL);
  k_deg<<<(EE + 255) / 256, 256, 0, stream>>>(rowArr, deg);
  k_scan1<<<SCB, 256, 0, stream>>>(deg, bsum);
  k_scan2<<<1, 64, 0, stream>>>(bsum, starts);
  k_scan3<<<SCB, 256, 0, stream>>>(deg, bsum, starts, cursor);
  k_scatter<<<(EE + 255) / 256, 256, 0, stream>>>(rowArr, colArr, cursor, eids, cols);
  k_gbounds<<<(NN + 255) / 256, 256, 0, stream>>>(batch, gstart);

  int nb64 = (NN + 63) / 64;
  int nb32 = (NN + 31) / 32;
  int nb16 = (NN + 15) / 16;
  int nbE  = (EE + 255) / 256;
  for (int l = 0; l < LL; l++) {
    k_ln_qkv_mfma<<<nb64, 256, 0, stream>>>(x,
        Wqf + (size_t)l * QKV_FRAG, bq + (size_t)l * HDIM,
        Wkf + (size_t)l * QKV_FRAG, bk + (size_t)l * HDIM,
        Wvf + (size_t)l * QKV_FRAG, bv + (size_t)l * HDIM,
        g1 + (size_t)l * HDIM, be1 + (size_t)l * HDIM, qb, kf8, vb);
    k_ebias<<<nbE, 256, 0, stream>>>(eids, e,
        Wcomb + (size_t)l * EDI * HH, bcomb + (size_t)l * HH, ebias);
    k_attn<<<nb16, 256, 0, stream>>>(qb, kf8, vb, cols, ebias, starts, ao);
    k_oproj_ffn<<<nb32, 256, 0, stream>>>(ao, Wof + (size_t)l * QKV_FRAG,
        bo + (size_t)l * HDIM,
        W1f + (size_t)l * FFN_FRAG1, b1 + (size_t)l * FFD,
        W2f + (size_t)l * FFN_FRAG2, b2 + (size_t)l * HDIM,
        g2 + (size_t)l * HDIM, be2 + (size_t)l * HDIM, x);
  }

  float* outx = (float*)d_out;
  float* outg = outx + (size_t)NN * HDIM;
  k_final<<<(NN + 63) / 64, 256, 0, stream>>>(x, gF, bF, outx);
  k_pool<<<GG, 512, 0, stream>>>(outx, gstart, outg);
}